// Round 1
// baseline (596.863 us; speedup 1.0000x reference)
//
#include <hip/hip_runtime.h>

// Problem constants: x [B=16, N=1024, F=256] fp32.
// Factored algorithm:
//   alpha = x @ Wa^T ; beta = x @ Wb^T ; unary = x @ Wu^T + bu
//   M[b]  = beta[b]^T @ unary[b]                       (F x F per batch)
//   d[r]  = alpha[r,:] . beta[r,:]                     (diagonal correction)
//   att   = (alpha @ M[b] - d * unary) / N
//   out   = att @ Wr^T + x

#define TPB 256
constexpr int BM = 64, BN = 64, BK = 16;

// C[m,n] = sum_k A[m,k]*B[n,k] (+bias[n]) (+res[m,n])   -- "NT" gemm, dot over shared dim
__global__ __launch_bounds__(256)
void gemm_nt(const float* __restrict__ A, const float* __restrict__ B,
             float* __restrict__ C, int M, int N, int K,
             const float* __restrict__ bias, const float* __restrict__ res)
{
    __shared__ float As[BM][BK + 1];
    __shared__ float Bs[BN][BK + 1];
    const int bm = blockIdx.y * BM, bn = blockIdx.x * BN;
    const int tid = threadIdx.x;
    const int tr = tid >> 4, tc = tid & 15;
    float acc[4][4] = {};
    for (int k0 = 0; k0 < K; k0 += BK) {
        for (int i = tid; i < BM * BK; i += TPB) {
            int m = i >> 4, k = i & 15;
            As[m][k] = A[(size_t)(bm + m) * K + k0 + k];
        }
        for (int i = tid; i < BN * BK; i += TPB) {
            int n = i >> 4, k = i & 15;
            Bs[n][k] = B[(size_t)(bn + n) * K + k0 + k];
        }
        __syncthreads();
#pragma unroll
        for (int k = 0; k < BK; k++) {
            float a[4], b[4];
#pragma unroll
            for (int i = 0; i < 4; i++) a[i] = As[tr * 4 + i][k];
#pragma unroll
            for (int j = 0; j < 4; j++) b[j] = Bs[tc * 4 + j][k];
#pragma unroll
            for (int i = 0; i < 4; i++)
#pragma unroll
                for (int j = 0; j < 4; j++) acc[i][j] += a[i] * b[j];
        }
        __syncthreads();
    }
#pragma unroll
    for (int i = 0; i < 4; i++) {
        int m = bm + tr * 4 + i;
#pragma unroll
        for (int j = 0; j < 4; j++) {
            int n = bn + tc * 4 + j;
            float v = acc[i][j];
            if (bias) v += bias[n];
            if (res)  v += res[(size_t)m * N + n];
            C[(size_t)m * N + n] = v;
        }
    }
}

// C_z[f,g] = sum_n A_z[n,f]*B_z[n,g]   ("TN": per-batch F x F outer-product accumulation)
__global__ __launch_bounds__(256)
void gemm_tn_batched(const float* __restrict__ A, const float* __restrict__ B,
                     float* __restrict__ C, int Kn, int F)
{
    const float* Ab = A + (size_t)blockIdx.z * Kn * F;
    const float* Bb = B + (size_t)blockIdx.z * Kn * F;
    float* Cb = C + (size_t)blockIdx.z * F * F;
    __shared__ float As[BK][BM + 1];  // As[k][f]
    __shared__ float Bs[BK][BN + 1];  // Bs[k][g]
    const int bf = blockIdx.y * BM, bg = blockIdx.x * BN;
    const int tid = threadIdx.x, tr = tid >> 4, tc = tid & 15;
    float acc[4][4] = {};
    for (int n0 = 0; n0 < Kn; n0 += BK) {
        for (int i = tid; i < BK * BM; i += TPB) {
            int k = i >> 6, f = i & 63;
            As[k][f] = Ab[(size_t)(n0 + k) * F + bf + f];
        }
        for (int i = tid; i < BK * BN; i += TPB) {
            int k = i >> 6, g = i & 63;
            Bs[k][g] = Bb[(size_t)(n0 + k) * F + bg + g];
        }
        __syncthreads();
#pragma unroll
        for (int k = 0; k < BK; k++) {
            float a[4], b[4];
#pragma unroll
            for (int i = 0; i < 4; i++) a[i] = As[k][tr * 4 + i];
#pragma unroll
            for (int j = 0; j < 4; j++) b[j] = Bs[k][tc * 4 + j];
#pragma unroll
            for (int i = 0; i < 4; i++)
#pragma unroll
                for (int j = 0; j < 4; j++) acc[i][j] += a[i] * b[j];
        }
        __syncthreads();
    }
#pragma unroll
    for (int i = 0; i < 4; i++)
#pragma unroll
        for (int j = 0; j < 4; j++)
            Cb[(size_t)(bf + tr * 4 + i) * F + bg + tc * 4 + j] = acc[i][j];
}

// C_z[m,n] = sum_k A_z[m,k]*B_z[k,n]   ("NN": alpha @ M[b])
__global__ __launch_bounds__(256)
void gemm_nn_batched(const float* __restrict__ A, const float* __restrict__ Bm,
                     float* __restrict__ C, int M, int N, int K)
{
    const float* Ab = A + (size_t)blockIdx.z * M * K;
    const float* Bb = Bm + (size_t)blockIdx.z * K * N;
    float* Cb = C + (size_t)blockIdx.z * M * N;
    __shared__ float As[BM][BK + 1];  // As[m][k]
    __shared__ float Bs[BK][BN + 1];  // Bs[k][n]
    const int bm = blockIdx.y * BM, bn = blockIdx.x * BN;
    const int tid = threadIdx.x, tr = tid >> 4, tc = tid & 15;
    float acc[4][4] = {};
    for (int k0 = 0; k0 < K; k0 += BK) {
        for (int i = tid; i < BM * BK; i += TPB) {
            int m = i >> 4, k = i & 15;
            As[m][k] = Ab[(size_t)(bm + m) * K + k0 + k];
        }
        for (int i = tid; i < BK * BN; i += TPB) {
            int k = i >> 6, n = i & 63;
            Bs[k][n] = Bb[(size_t)(k0 + k) * N + bn + n];
        }
        __syncthreads();
#pragma unroll
        for (int k = 0; k < BK; k++) {
            float a[4], b[4];
#pragma unroll
            for (int i = 0; i < 4; i++) a[i] = As[tr * 4 + i][k];
#pragma unroll
            for (int j = 0; j < 4; j++) b[j] = Bs[k][tc * 4 + j];
#pragma unroll
            for (int i = 0; i < 4; i++)
#pragma unroll
                for (int j = 0; j < 4; j++) acc[i][j] += a[i] * b[j];
        }
        __syncthreads();
    }
#pragma unroll
    for (int i = 0; i < 4; i++)
#pragma unroll
        for (int j = 0; j < 4; j++)
            Cb[(size_t)(bm + tr * 4 + i) * N + bn + tc * 4 + j] = acc[i][j];
}

// One wave per row r: d = alpha[r,:].beta[r,:]; T[r,:] = (T[r,:] - d*unary[r,:]) / N
__global__ __launch_bounds__(256)
void att_fix(const float* __restrict__ alpha, const float* __restrict__ beta,
             const float* __restrict__ unary, float* __restrict__ T, float invN)
{
    const int row = blockIdx.x * 4 + (threadIdx.x >> 6);
    const int lane = threadIdx.x & 63;
    const size_t base = (size_t)row * 256;
    const float4* a4 = (const float4*)(alpha + base);
    const float4* b4 = (const float4*)(beta + base);
    float4 av = a4[lane], bv = b4[lane];
    float d = av.x * bv.x + av.y * bv.y + av.z * bv.z + av.w * bv.w;
#pragma unroll
    for (int off = 32; off; off >>= 1) d += __shfl_xor(d, off);
    const float4* u4 = (const float4*)(unary + base);
    float4* t4 = (float4*)(T + base);
    float4 uv = u4[lane], tv = t4[lane];
    tv.x = (tv.x - d * uv.x) * invN;
    tv.y = (tv.y - d * uv.y) * invN;
    tv.z = (tv.z - d * uv.z) * invN;
    tv.w = (tv.w - d * uv.w) * invN;
    t4[lane] = tv;
}

extern "C" void kernel_launch(void* const* d_in, const int* in_sizes, int n_in,
                              void* d_out, int out_size, void* d_ws, size_t ws_size,
                              hipStream_t stream)
{
    const float* x  = (const float*)d_in[0];
    const float* Wa = (const float*)d_in[1];
    const float* Wb = (const float*)d_in[2];
    const float* Wu = (const float*)d_in[3];
    const float* bu = (const float*)d_in[4];
    const float* Wr = (const float*)d_in[5];
    float* out = (float*)d_out;

    const int B = 16, N = 1024, F = 256;
    const int R = B * N;  // 16384 rows

    float* ws    = (float*)d_ws;
    float* alpha = ws;                        // R*F
    float* beta  = alpha + (size_t)R * F;     // R*F
    float* unary = beta  + (size_t)R * F;     // R*F
    float* T     = unary + (size_t)R * F;     // R*F
    float* Mb    = T     + (size_t)R * F;     // B*F*F
    // total: 4*R*F + B*F*F = 17,825,792 floats ~= 68 MB

    dim3 blk(TPB);
    dim3 g1(F / BN, R / BM);       // (4, 256)
    gemm_nt<<<g1, blk, 0, stream>>>(x, Wa, alpha, R, F, F, nullptr, nullptr);
    gemm_nt<<<g1, blk, 0, stream>>>(x, Wb, beta,  R, F, F, nullptr, nullptr);
    gemm_nt<<<g1, blk, 0, stream>>>(x, Wu, unary, R, F, F, bu, nullptr);

    dim3 g2(F / BN, F / BM, B);    // (4, 4, 16)
    gemm_tn_batched<<<g2, blk, 0, stream>>>(beta, unary, Mb, N, F);

    dim3 g3(F / BN, N / BM, B);    // (4, 16, 16)
    gemm_nn_batched<<<g3, blk, 0, stream>>>(alpha, Mb, T, N, F, F);

    att_fix<<<R / 4, blk, 0, stream>>>(alpha, beta, unary, T, 1.0f / N);

    gemm_nt<<<g1, blk, 0, stream>>>(T, Wr, out, R, F, F, nullptr, x);
}

// Round 2
// 150.801 us; speedup vs baseline: 3.9580x; 3.9580x over previous
//
#include <hip/hip_runtime.h>

// x [B=16, N=1024, F=256] fp32.  Factored algorithm, bf16 MFMA:
//   xb = bf16(x); W*b = bf16(W*)
//   alpha|beta|unary = xb @ W*b^T (+bu)          [fused proj kernel, bf16 out]
//   d[r] = alpha[r,:].beta[r,:]                  [diag correction]
//   Mt[b] = unary[b]^T @ beta[b]  (= M^T)        [split-K=4, fp32 partials]
//   T = (alpha @ Mt^T - d*unary)/N               [NT gemm, diag epilogue]
//   out = T @ Wr^T + x                           [NT gemm, fp32 residual]

typedef __bf16 bf16;
typedef float floatx4 __attribute__((ext_vector_type(4)));
typedef bf16 bf16x8 __attribute__((ext_vector_type(8)));
typedef bf16 bf16x4 __attribute__((ext_vector_type(4)));

constexpr int FD = 256;       // feature dim
constexpr int NB = 16;        // batches
constexpr int NN = 1024;      // tokens per batch
constexpr int RR = NB * NN;   // 16384 rows

// ---------------- converts ----------------
__global__ __launch_bounds__(256) void cvt_x(const float* __restrict__ x, bf16* __restrict__ xb) {
    int i = (blockIdx.x * 256 + threadIdx.x) * 4;
    float4 v = *(const float4*)&x[i];
    bf16x4 o = { (bf16)v.x, (bf16)v.y, (bf16)v.z, (bf16)v.w };
    *(bf16x4*)&xb[i] = o;
}

__global__ __launch_bounds__(256) void cvt_w(const float* Wa, const float* Wb, const float* Wu, const float* Wr,
                                             bf16* Wab, bf16* Wbb, bf16* Wub, bf16* Wrb) {
    const float* src; bf16* dst;
    switch (blockIdx.y) {
        case 0: src = Wa; dst = Wab; break;
        case 1: src = Wb; dst = Wbb; break;
        case 2: src = Wu; dst = Wub; break;
        default: src = Wr; dst = Wrb; break;
    }
    int i = (blockIdx.x * 256 + threadIdx.x) * 4;
    float4 v = *(const float4*)&src[i];
    bf16x4 o = { (bf16)v.x, (bf16)v.y, (bf16)v.z, (bf16)v.w };
    *(bf16x4*)&dst[i] = o;
}

// ---------------- fused 3-way projection: {alpha,beta,unary} = xb @ W^T ----------------
// BM=128 rows, BN=64 cols, BK=32. 4 waves, wave tile 32x64 per weight.
__global__ __launch_bounds__(256)
void proj_mfma(const bf16* __restrict__ A,
               const bf16* __restrict__ W0, const bf16* __restrict__ W1, const bf16* __restrict__ W2,
               bf16* __restrict__ O0, bf16* __restrict__ O1, bf16* __restrict__ O2,
               const float* __restrict__ bu)
{
    constexpr int BM = 128, BN = 64, BK = 32, LDK = 40;
    __shared__ bf16 As[BM][LDK];
    __shared__ bf16 Bs[3][BN][LDK];
    const int tid = threadIdx.x;
    const int wave = tid >> 6, lane = tid & 63;
    const int q = lane >> 4, l16 = lane & 15;
    const int bm = blockIdx.y * BM, bn = blockIdx.x * BN;
    const bf16* Wp[3] = { W0, W1, W2 };

    floatx4 acc[3][2][4] = {};

    for (int k0 = 0; k0 < FD; k0 += BK) {
        { // stage A: 128 rows x 4 chunks(16B) = 512 chunks
            int c = tid;
            int row = c >> 2, k8 = (c & 3) * 8;
            *(int4*)&As[row][k8] = *(const int4*)&A[(size_t)(bm + row) * FD + k0 + k8];
            c = tid + 256; row = c >> 2; k8 = (c & 3) * 8;
            *(int4*)&As[row][k8] = *(const int4*)&A[(size_t)(bm + row) * FD + k0 + k8];
        }
        #pragma unroll
        for (int w = 0; w < 3; w++) { // stage each W: 64 rows x 4 chunks = 256 chunks
            int row = tid >> 2, k8 = (tid & 3) * 8;
            *(int4*)&Bs[w][row][k8] = *(const int4*)&Wp[w][(size_t)(bn + row) * FD + k0 + k8];
        }
        __syncthreads();
        bf16x8 af[2];
        #pragma unroll
        for (int mi = 0; mi < 2; mi++)
            af[mi] = *(const bf16x8*)&As[wave * 32 + mi * 16 + l16][q * 8];
        #pragma unroll
        for (int w = 0; w < 3; w++) {
            bf16x8 bq[4];
            #pragma unroll
            for (int nj = 0; nj < 4; nj++)
                bq[nj] = *(const bf16x8*)&Bs[w][nj * 16 + l16][q * 8];
            #pragma unroll
            for (int mi = 0; mi < 2; mi++)
                #pragma unroll
                for (int nj = 0; nj < 4; nj++)
                    acc[w][mi][nj] = __builtin_amdgcn_mfma_f32_16x16x32_bf16(af[mi], bq[nj], acc[w][mi][nj], 0, 0, 0);
        }
        __syncthreads();
    }

    bf16* Op[3] = { O0, O1, O2 };
    #pragma unroll
    for (int w = 0; w < 3; w++) {
        #pragma unroll
        for (int mi = 0; mi < 2; mi++)
            #pragma unroll
            for (int i = 0; i < 4; i++) {
                int m = bm + wave * 32 + mi * 16 + q * 4 + i;
                #pragma unroll
                for (int nj = 0; nj < 4; nj++) {
                    int n = bn + nj * 16 + l16;
                    float v = acc[w][mi][nj][i];
                    if (w == 2) v += bu[n];
                    Op[w][(size_t)m * FD + n] = (bf16)v;
                }
            }
    }
}

// ---------------- generic NT gemm: C[m,n] = sum_k A[m,k]*B[n,k], with epilogues ----------------
// MODE 0: plain->bf16  | MODE 2: T=(acc-d[m]*U[m,n])/N -> bf16 | MODE 3: acc+res -> f32
template<int MODE>
__global__ __launch_bounds__(256)
void gemm_nt_mfma(const bf16* __restrict__ A, const bf16* __restrict__ Bmat, void* __restrict__ Cout,
                  const float* __restrict__ dvec, const bf16* __restrict__ U,
                  const float* __restrict__ res, int batchB)
{
    constexpr int BM = 128, BN = 64, BK = 32, LDK = 40;
    __shared__ bf16 As[BM][LDK];
    __shared__ bf16 Bs[BN][LDK];
    const int tid = threadIdx.x;
    const int wave = tid >> 6, lane = tid & 63;
    const int q = lane >> 4, l16 = lane & 15;
    const int bm = blockIdx.y * BM, bn = blockIdx.x * BN;
    const bf16* Bp = Bmat + (batchB ? (size_t)(bm >> 10) * FD * FD : 0);

    floatx4 acc[2][4] = {};

    for (int k0 = 0; k0 < FD; k0 += BK) {
        {
            int c = tid;
            int row = c >> 2, k8 = (c & 3) * 8;
            *(int4*)&As[row][k8] = *(const int4*)&A[(size_t)(bm + row) * FD + k0 + k8];
            c = tid + 256; row = c >> 2; k8 = (c & 3) * 8;
            *(int4*)&As[row][k8] = *(const int4*)&A[(size_t)(bm + row) * FD + k0 + k8];
            int rb = tid >> 2, kb8 = (tid & 3) * 8;
            *(int4*)&Bs[rb][kb8] = *(const int4*)&Bp[(size_t)(bn + rb) * FD + k0 + kb8];
        }
        __syncthreads();
        bf16x8 af[2], bq[4];
        #pragma unroll
        for (int mi = 0; mi < 2; mi++)
            af[mi] = *(const bf16x8*)&As[wave * 32 + mi * 16 + l16][q * 8];
        #pragma unroll
        for (int nj = 0; nj < 4; nj++)
            bq[nj] = *(const bf16x8*)&Bs[nj * 16 + l16][q * 8];
        #pragma unroll
        for (int mi = 0; mi < 2; mi++)
            #pragma unroll
            for (int nj = 0; nj < 4; nj++)
                acc[mi][nj] = __builtin_amdgcn_mfma_f32_16x16x32_bf16(af[mi], bq[nj], acc[mi][nj], 0, 0, 0);
        __syncthreads();
    }

    #pragma unroll
    for (int mi = 0; mi < 2; mi++)
        #pragma unroll
        for (int i = 0; i < 4; i++) {
            int m = bm + wave * 32 + mi * 16 + q * 4 + i;
            float dm = (MODE == 2) ? dvec[m] : 0.0f;
            #pragma unroll
            for (int nj = 0; nj < 4; nj++) {
                int n = bn + nj * 16 + l16;
                float v = acc[mi][nj][i];
                if (MODE == 2) {
                    v = (v - dm * (float)U[(size_t)m * FD + n]) * (1.0f / 1024.0f);
                    ((bf16*)Cout)[(size_t)m * FD + n] = (bf16)v;
                } else if (MODE == 3) {
                    ((float*)Cout)[(size_t)m * FD + n] = v + res[(size_t)m * FD + n];
                } else {
                    ((bf16*)Cout)[(size_t)m * FD + n] = (bf16)v;
                }
            }
        }
}

// ---------------- TN gemm (split-K): Mt[b][g][f] += sum_n unary[b][n][g] * beta[b][n][f] ----------------
// grid (F/64, F/64, B*4); z = b*4 + chunk; chunk covers n in [chunk*256, chunk*256+256)
__global__ __launch_bounds__(256)
void gemm_tn_mfma(const bf16* __restrict__ Uall, const bf16* __restrict__ Ball, float* __restrict__ Mpart)
{
    constexpr int BG = 64, BF = 64, BK = 32, LDK = 40, CHUNK = 256;
    __shared__ bf16 Ags[BG][LDK];  // [g][n-local]
    __shared__ bf16 Bfs[BF][LDK];  // [f][n-local]
    const int tid = threadIdx.x;
    const int wave = tid >> 6, lane = tid & 63;
    const int q = lane >> 4, l16 = lane & 15;
    const int b = blockIdx.z >> 2, chunk = blockIdx.z & 3;
    const int bg = blockIdx.y * BG, bfo = blockIdx.x * BF;
    const bf16* Ub = Uall + (size_t)b * NN * FD;
    const bf16* Bt = Ball + (size_t)b * NN * FD;

    floatx4 acc[4] = {};

    const int n0base = chunk * CHUNK;
    for (int nc = 0; nc < CHUNK; nc += BK) {
        { // stage transposed: 32 n-rows x 8 chunks(8 bf16) each for A and B
            int nr = tid >> 3, g8 = (tid & 7) * 8;
            bf16x8 va = *(const bf16x8*)&Ub[(size_t)(n0base + nc + nr) * FD + bg + g8];
            bf16x8 vb = *(const bf16x8*)&Bt[(size_t)(n0base + nc + nr) * FD + bfo + g8];
            #pragma unroll
            for (int j = 0; j < 8; j++) {
                Ags[g8 + j][nr] = va[j];
                Bfs[g8 + j][nr] = vb[j];
            }
        }
        __syncthreads();
        bf16x8 af = *(const bf16x8*)&Ags[wave * 16 + l16][q * 8];
        #pragma unroll
        for (int fj = 0; fj < 4; fj++) {
            bf16x8 bq = *(const bf16x8*)&Bfs[fj * 16 + l16][q * 8];
            acc[fj] = __builtin_amdgcn_mfma_f32_16x16x32_bf16(af, bq, acc[fj], 0, 0, 0);
        }
        __syncthreads();
    }

    float* P = Mpart + (size_t)chunk * (NB * FD * FD) + (size_t)b * FD * FD;
    #pragma unroll
    for (int i = 0; i < 4; i++) {
        int g = bg + wave * 16 + q * 4 + i;
        #pragma unroll
        for (int fj = 0; fj < 4; fj++) {
            int f = bfo + fj * 16 + l16;
            P[(size_t)g * FD + f] = acc[fj][i];
        }
    }
}

__global__ __launch_bounds__(256) void reduce_M(const float* __restrict__ Mpart, bf16* __restrict__ Mt) {
    int i = (blockIdx.x * 256 + threadIdx.x) * 4;
    const size_t S = (size_t)NB * FD * FD;
    float4 a = *(const float4*)&Mpart[i];
    float4 c = *(const float4*)&Mpart[S + i];
    float4 e = *(const float4*)&Mpart[2 * S + i];
    float4 g = *(const float4*)&Mpart[3 * S + i];
    bf16x4 o = { (bf16)(a.x + c.x + e.x + g.x), (bf16)(a.y + c.y + e.y + g.y),
                 (bf16)(a.z + c.z + e.z + g.z), (bf16)(a.w + c.w + e.w + g.w) };
    *(bf16x4*)&Mt[i] = o;
}

// ---------------- per-row diag dot: d[r] = alpha[r,:].beta[r,:] ----------------
__global__ __launch_bounds__(256)
void d_dot(const bf16* __restrict__ alpha, const bf16* __restrict__ beta, float* __restrict__ d) {
    const int row = blockIdx.x * 4 + (threadIdx.x >> 6);
    const int lane = threadIdx.x & 63;
    const size_t base = (size_t)row * FD;
    bf16x4 av = *(const bf16x4*)&alpha[base + lane * 4];
    bf16x4 bv = *(const bf16x4*)&beta[base + lane * 4];
    float s = (float)av[0] * (float)bv[0] + (float)av[1] * (float)bv[1] +
              (float)av[2] * (float)bv[2] + (float)av[3] * (float)bv[3];
    #pragma unroll
    for (int off = 32; off; off >>= 1) s += __shfl_xor(s, off);
    if (lane == 0) d[row] = s;
}

extern "C" void kernel_launch(void* const* d_in, const int* in_sizes, int n_in,
                              void* d_out, int out_size, void* d_ws, size_t ws_size,
                              hipStream_t stream)
{
    const float* x  = (const float*)d_in[0];
    const float* Wa = (const float*)d_in[1];
    const float* Wb = (const float*)d_in[2];
    const float* Wu = (const float*)d_in[3];
    const float* bu = (const float*)d_in[4];
    const float* Wr = (const float*)d_in[5];
    float* out = (float*)d_out;

    char* w = (char*)d_ws;
    bf16* xb    = (bf16*)w;                 w += (size_t)RR * FD * 2;   // 8 MB
    bf16* Wab   = (bf16*)w;                 w += (size_t)FD * FD * 2;
    bf16* Wbb   = (bf16*)w;                 w += (size_t)FD * FD * 2;
    bf16* Wub   = (bf16*)w;                 w += (size_t)FD * FD * 2;
    bf16* Wrb   = (bf16*)w;                 w += (size_t)FD * FD * 2;   // +0.5 MB
    bf16* alpha = (bf16*)w;                 w += (size_t)RR * FD * 2;   // 8 MB
    bf16* beta  = (bf16*)w;                 w += (size_t)RR * FD * 2;   // 8 MB
    bf16* unary = (bf16*)w;                 w += (size_t)RR * FD * 2;   // 8 MB
    bf16* Tb    = (bf16*)w;                 w += (size_t)RR * FD * 2;   // 8 MB
    float* dv   = (float*)w;                w += (size_t)RR * 4;        // 64 KB
    float* Mpart= (float*)w;                w += (size_t)4 * NB * FD * FD * 4; // 16 MB
    bf16* Mt    = (bf16*)w;                 w += (size_t)NB * FD * FD * 2;     // 2 MB

    dim3 blk(256);

    cvt_x<<<dim3(RR * FD / 1024), blk, 0, stream>>>(x, xb);
    cvt_w<<<dim3(FD * FD / 1024, 4), blk, 0, stream>>>(Wa, Wb, Wu, Wr, Wab, Wbb, Wub, Wrb);

    proj_mfma<<<dim3(FD / 64, RR / 128), blk, 0, stream>>>(xb, Wab, Wbb, Wub, alpha, beta, unary, bu);

    d_dot<<<dim3(RR / 4), blk, 0, stream>>>(alpha, beta, dv);

    gemm_tn_mfma<<<dim3(FD / 64, FD / 64, NB * 4), blk, 0, stream>>>(unary, beta, Mpart);
    reduce_M<<<dim3(NB * FD * FD / 1024), blk, 0, stream>>>(Mpart, Mt);

    // T = (alpha @ Mt^T - d*unary)/N   (batched B: Mt per batch, rows g=out-col n, cols k)
    gemm_nt_mfma<2><<<dim3(FD / 64, RR / 128), blk, 0, stream>>>(alpha, Mt, Tb, dv, unary, nullptr, 1);

    // out = Tb @ Wr^T + x
    gemm_nt_mfma<3><<<dim3(FD / 64, RR / 128), blk, 0, stream>>>(Tb, Wrb, out, nullptr, nullptr, x, 0);
}